// Round 1
// baseline (116.304 us; speedup 1.0000x reference)
//
#include <hip/hip_runtime.h>

#define DIN  128
#define DOUT 32

// ---------------- Kernel 1: HW = H @ W  (dense fp32 GEMM, vector ALU) -------
// 8 rows per 256-thread block. W (128x32 = 16KB) and 8 H rows (4KB) in LDS.
// Each thread produces one output element: out[row0+ (tid>>5)][tid&31].
__global__ __launch_bounds__(256) void gemm_hw_kernel(
    const float* __restrict__ H, const float* __restrict__ W,
    float* __restrict__ HW, int n)
{
    __shared__ float Wlds[DIN * DOUT];   // 16 KB
    __shared__ float Hlds[8 * DIN];      // 4 KB
    const int tid = threadIdx.x;

    // Stage W: 4096 floats / 256 threads = 16 each, coalesced.
    #pragma unroll
    for (int i = tid; i < DIN * DOUT; i += 256) Wlds[i] = W[i];

    const int row0 = blockIdx.x * 8;
    // Stage 8 H rows: 8*128 = 1024 floats = 256 float4, one per thread.
    const size_t f4_base = (size_t)row0 * (DIN / 4);
    const size_t f4_idx  = f4_base + tid;
    if (f4_idx < (size_t)n * (DIN / 4)) {
        reinterpret_cast<float4*>(Hlds)[tid] =
            reinterpret_cast<const float4*>(H)[f4_idx];
    }
    __syncthreads();

    const int r = tid >> 5;   // 0..7
    const int c = tid & 31;   // 0..31
    float acc = 0.f;
    #pragma unroll
    for (int k = 0; k < DIN; ++k)
        acc = fmaf(Hlds[r * DIN + k], Wlds[k * DOUT + c], acc);

    const int row = row0 + r;
    if (row < n) HW[(size_t)row * DOUT + c] = acc;
}

// ---------------- Kernel 2: out = A_csr @ HW  (SpMM) ------------------------
// One thread per output element. 32 lanes share a row; per edge they read one
// contiguous 128B row of HW (coalesced, L2/L3-served since HW is 12.8 MB).
__global__ __launch_bounds__(256) void spmm_kernel(
    const float* __restrict__ HW, const int* __restrict__ rowPtr,
    const int* __restrict__ colIdx, const float* __restrict__ val,
    float* __restrict__ out, int n)
{
    const int gid = blockIdx.x * 256 + threadIdx.x;
    const int row = gid >> 5;
    if (row >= n) return;
    const int c = gid & 31;

    const int start = rowPtr[row];
    const int end   = rowPtr[row + 1];
    float acc = 0.f;
    for (int e = start; e < end; ++e) {
        const int   cidx = colIdx[e];
        const float v    = val[e];
        acc = fmaf(v, HW[(size_t)cidx * DOUT + c], acc);
    }
    out[(size_t)row * DOUT + c] = acc;
}

// ---------------- Fallback: fused (only if ws too small) --------------------
__global__ __launch_bounds__(256) void fused_kernel(
    const float* __restrict__ H, const float* __restrict__ W,
    const int* __restrict__ rowPtr, const int* __restrict__ colIdx,
    const float* __restrict__ val, float* __restrict__ out, int n)
{
    __shared__ float Wlds[DIN * DOUT];
    for (int i = threadIdx.x; i < DIN * DOUT; i += 256) Wlds[i] = W[i];
    __syncthreads();

    const int gid = blockIdx.x * 256 + threadIdx.x;
    const int row = gid >> 5;
    if (row >= n) return;
    const int c = gid & 31;

    const int start = rowPtr[row];
    const int end   = rowPtr[row + 1];
    float acc = 0.f;
    for (int e = start; e < end; ++e) {
        const int   cidx = colIdx[e];
        const float v    = val[e];
        const float* h = H + (size_t)cidx * DIN;
        float dot = 0.f;
        #pragma unroll 8
        for (int k = 0; k < DIN; ++k)
            dot = fmaf(h[k], Wlds[k * DOUT + c], dot);
        acc = fmaf(v, dot, acc);
    }
    out[(size_t)row * DOUT + c] = acc;
}

extern "C" void kernel_launch(void* const* d_in, const int* in_sizes, int n_in,
                              void* d_out, int out_size, void* d_ws, size_t ws_size,
                              hipStream_t stream)
{
    const float* H      = (const float*)d_in[0];
    const float* W      = (const float*)d_in[1];
    const int*   rowPtr = (const int*)d_in[2];
    const int*   colIdx = (const int*)d_in[3];
    const float* val    = (const float*)d_in[4];
    float*       out    = (float*)d_out;

    const int n = in_sizes[2] - 1;           // rowPtr has N+1 entries
    const size_t hw_bytes = (size_t)n * DOUT * sizeof(float);

    const int spmm_blocks = (int)(((size_t)n * DOUT + 255) / 256);

    if (ws_size >= hw_bytes) {
        float* HW = (float*)d_ws;
        gemm_hw_kernel<<<(n + 7) / 8, 256, 0, stream>>>(H, W, HW, n);
        spmm_kernel<<<spmm_blocks, 256, 0, stream>>>(HW, rowPtr, colIdx, val, out, n);
    } else {
        fused_kernel<<<spmm_blocks, 256, 0, stream>>>(H, W, rowPtr, colIdx, val, out, n);
    }
}

// Round 2
// 72.135 us; speedup vs baseline: 1.6123x; 1.6123x over previous
//
#include <hip/hip_runtime.h>

#define DIN  128
#define DOUT 32
#define BM   64          // rows per GEMM block
#define LDH4 34          // float4 stride of H tile (136 floats, 16B-aligned, 2-way-free banks)

// ---------------- Kernel 1: HW = H @ W  (dense fp32, vector ALU) ------------
// 128 threads/block, 64 rows/block. Thread computes 4 rows x 4 cols.
// Per 4k-step: 4 ds_read_b128 (H) + 4 ds_read_b128 (W) + 64 scalar FMAs
// -> VALU-issue-bound (8:1 FMA:LDS inst ratio).
__global__ __launch_bounds__(128) void gemm_hw_kernel(
    const float* __restrict__ H, const float* __restrict__ W,
    float* __restrict__ HW, int n)
{
    __shared__ float4 H4lds[BM * LDH4];        // 34816 B
    __shared__ float4 W4lds[DIN * (DOUT / 4)]; // 16384 B
    const int tid  = threadIdx.x;
    const int row0 = blockIdx.x * BM;

    // Stage W: 1024 float4 / 128 threads = 8 each, coalesced.
    #pragma unroll
    for (int i = tid; i < DIN * (DOUT / 4); i += 128)
        W4lds[i] = reinterpret_cast<const float4*>(W)[i];

    // Stage H: 64 rows x 32 f4 = 2048 f4 / 128 threads = 16 each.
    #pragma unroll
    for (int i = tid; i < BM * (DIN / 4); i += 128) {
        const int r  = i >> 5;
        const int c4 = i & 31;
        int gr = row0 + r;
        if (gr >= n) gr = n - 1;               // clamp (reads only, stores guarded)
        H4lds[r * LDH4 + c4] =
            reinterpret_cast<const float4*>(H)[(size_t)gr * (DIN / 4) + c4];
    }
    __syncthreads();

    const int rg = tid >> 3;   // 0..15
    const int cg = tid & 7;    // 0..7
    const int r0 = rg * 4;

    float4 acc0 = {0.f, 0.f, 0.f, 0.f};
    float4 acc1 = {0.f, 0.f, 0.f, 0.f};
    float4 acc2 = {0.f, 0.f, 0.f, 0.f};
    float4 acc3 = {0.f, 0.f, 0.f, 0.f};

    #pragma unroll 8
    for (int k4 = 0; k4 < DIN / 4; ++k4) {
        const float4 h0 = H4lds[(r0 + 0) * LDH4 + k4];
        const float4 h1 = H4lds[(r0 + 1) * LDH4 + k4];
        const float4 h2 = H4lds[(r0 + 2) * LDH4 + k4];
        const float4 h3 = H4lds[(r0 + 3) * LDH4 + k4];
        const float4 w0 = W4lds[(k4 * 4 + 0) * 8 + cg];
        const float4 w1 = W4lds[(k4 * 4 + 1) * 8 + cg];
        const float4 w2 = W4lds[(k4 * 4 + 2) * 8 + cg];
        const float4 w3 = W4lds[(k4 * 4 + 3) * 8 + cg];

        #define FMA4(A, S, WV)                      \
            A.x = fmaf(S, WV.x, A.x);               \
            A.y = fmaf(S, WV.y, A.y);               \
            A.z = fmaf(S, WV.z, A.z);               \
            A.w = fmaf(S, WV.w, A.w);
        FMA4(acc0, h0.x, w0) FMA4(acc0, h0.y, w1) FMA4(acc0, h0.z, w2) FMA4(acc0, h0.w, w3)
        FMA4(acc1, h1.x, w0) FMA4(acc1, h1.y, w1) FMA4(acc1, h1.z, w2) FMA4(acc1, h1.w, w3)
        FMA4(acc2, h2.x, w0) FMA4(acc2, h2.y, w1) FMA4(acc2, h2.z, w2) FMA4(acc2, h2.w, w3)
        FMA4(acc3, h3.x, w0) FMA4(acc3, h3.y, w1) FMA4(acc3, h3.z, w2) FMA4(acc3, h3.w, w3)
        #undef FMA4
    }

    float4* HW4 = reinterpret_cast<float4*>(HW);
    const int c4out = cg;
    #define STORE(I, A)                                                      \
        { const int rr = row0 + r0 + I;                                      \
          if (rr < n) HW4[(size_t)rr * (DOUT / 4) + c4out] = A; }
    STORE(0, acc0) STORE(1, acc1) STORE(2, acc2) STORE(3, acc3)
    #undef STORE
}

// ---------------- Kernel 2: out = A_csr @ HW  (SpMM, float4 + deep unroll) --
__global__ __launch_bounds__(256) void spmm_kernel(
    const float* __restrict__ HWf, const int* __restrict__ rowPtr,
    const int* __restrict__ colIdx, const float* __restrict__ val,
    float* __restrict__ out, int n)
{
    const float4* HW4 = reinterpret_cast<const float4*>(HWf);
    const int gid = blockIdx.x * 256 + threadIdx.x;
    const int row = gid >> 3;
    if (row >= n) return;
    const int cg = gid & 7;

    const int start = rowPtr[row];
    const int end   = rowPtr[row + 1];
    float4 acc = {0.f, 0.f, 0.f, 0.f};

    #define GATHER_FMA(E)                                                    \
        { const int   c_ = colIdx[E];                                        \
          const float v_ = val[E];                                           \
          const float4 h_ = HW4[(size_t)c_ * (DOUT / 4) + cg];               \
          acc.x = fmaf(v_, h_.x, acc.x);                                     \
          acc.y = fmaf(v_, h_.y, acc.y);                                     \
          acc.z = fmaf(v_, h_.z, acc.z);                                     \
          acc.w = fmaf(v_, h_.w, acc.w); }

    int e = start;
    for (; e + 8 <= end; e += 8) {
        GATHER_FMA(e + 0) GATHER_FMA(e + 1) GATHER_FMA(e + 2) GATHER_FMA(e + 3)
        GATHER_FMA(e + 4) GATHER_FMA(e + 5) GATHER_FMA(e + 6) GATHER_FMA(e + 7)
    }
    for (; e + 4 <= end; e += 4) {
        GATHER_FMA(e + 0) GATHER_FMA(e + 1) GATHER_FMA(e + 2) GATHER_FMA(e + 3)
    }
    for (; e < end; ++e) { GATHER_FMA(e) }
    #undef GATHER_FMA

    reinterpret_cast<float4*>(out)[(size_t)row * (DOUT / 4) + cg] = acc;
}

// ---------------- Fallback: fused (only if ws too small) --------------------
__global__ __launch_bounds__(256) void fused_kernel(
    const float* __restrict__ H, const float* __restrict__ W,
    const int* __restrict__ rowPtr, const int* __restrict__ colIdx,
    const float* __restrict__ val, float* __restrict__ out, int n)
{
    __shared__ float Wlds[DIN * DOUT];
    for (int i = threadIdx.x; i < DIN * DOUT; i += 256) Wlds[i] = W[i];
    __syncthreads();

    const int gid = blockIdx.x * 256 + threadIdx.x;
    const int row = gid >> 5;
    if (row >= n) return;
    const int c = gid & 31;

    const int start = rowPtr[row];
    const int end   = rowPtr[row + 1];
    float acc = 0.f;
    for (int e = start; e < end; ++e) {
        const int   cidx = colIdx[e];
        const float v    = val[e];
        const float* h = H + (size_t)cidx * DIN;
        float dot = 0.f;
        #pragma unroll 8
        for (int k = 0; k < DIN; ++k)
            dot = fmaf(h[k], Wlds[k * DOUT + c], dot);
        acc = fmaf(v, dot, acc);
    }
    out[(size_t)row * DOUT + c] = acc;
}

extern "C" void kernel_launch(void* const* d_in, const int* in_sizes, int n_in,
                              void* d_out, int out_size, void* d_ws, size_t ws_size,
                              hipStream_t stream)
{
    const float* H      = (const float*)d_in[0];
    const float* W      = (const float*)d_in[1];
    const int*   rowPtr = (const int*)d_in[2];
    const int*   colIdx = (const int*)d_in[3];
    const float* val    = (const float*)d_in[4];
    float*       out    = (float*)d_out;

    const int n = in_sizes[2] - 1;           // rowPtr has N+1 entries
    const size_t hw_bytes = (size_t)n * DOUT * sizeof(float);

    if (ws_size >= hw_bytes) {
        float* HW = (float*)d_ws;
        gemm_hw_kernel<<<(n + BM - 1) / BM, 128, 0, stream>>>(H, W, HW, n);
        const int spmm_blocks = (int)(((size_t)n * (DOUT / 4) + 255) / 256);
        spmm_kernel<<<spmm_blocks, 256, 0, stream>>>(HW, rowPtr, colIdx, val, out, n);
    } else {
        const int blocks = (int)(((size_t)n * DOUT + 255) / 256);
        fused_kernel<<<blocks, 256, 0, stream>>>(H, W, rowPtr, colIdx, val, out, n);
    }
}

// Round 3
// 55.253 us; speedup vs baseline: 2.1049x; 1.3055x over previous
//
#include <hip/hip_runtime.h>

#define DIN  128
#define DOUT 32

// ---------------- Kernel 1: HW = H @ W  (fp32 vector ALU) -------------------
// 256 threads/block, 128 rows/block. Thread = (rg 0..31, cg 0..7), computes
// 4 rows x 4 cols. H read directly from global (b128, L1 broadcasts across the
// 8 cg-lanes sharing a row); only W (16 KB) lives in LDS, conflict-free.
__global__ __launch_bounds__(256) void gemm_hw_kernel(
    const float* __restrict__ H, const float* __restrict__ W,
    float* __restrict__ HW, int n)
{
    __shared__ float4 W4lds[DIN * (DOUT / 4)];   // [k][cg], 16 KB
    const int tid = threadIdx.x;

    #pragma unroll
    for (int i = tid; i < DIN * (DOUT / 4); i += 256)
        W4lds[i] = reinterpret_cast<const float4*>(W)[i];
    __syncthreads();

    const int rg = tid >> 3;      // 0..31
    const int cg = tid & 7;       // 0..7
    const int r0 = blockIdx.x * 128 + rg * 4;

    // Clamp read rows (stores are guarded).
    const int rr0 = (r0 + 0 < n) ? r0 + 0 : n - 1;
    const int rr1 = (r0 + 1 < n) ? r0 + 1 : n - 1;
    const int rr2 = (r0 + 2 < n) ? r0 + 2 : n - 1;
    const int rr3 = (r0 + 3 < n) ? r0 + 3 : n - 1;

    const float4* __restrict__ H4 = reinterpret_cast<const float4*>(H);
    const float4* __restrict__ h0p = H4 + (size_t)rr0 * (DIN / 4);
    const float4* __restrict__ h1p = H4 + (size_t)rr1 * (DIN / 4);
    const float4* __restrict__ h2p = H4 + (size_t)rr2 * (DIN / 4);
    const float4* __restrict__ h3p = H4 + (size_t)rr3 * (DIN / 4);

    float4 acc0 = {0.f, 0.f, 0.f, 0.f};
    float4 acc1 = {0.f, 0.f, 0.f, 0.f};
    float4 acc2 = {0.f, 0.f, 0.f, 0.f};
    float4 acc3 = {0.f, 0.f, 0.f, 0.f};

    #pragma unroll 2
    for (int k4 = 0; k4 < DIN / 4; ++k4) {
        const float4 h0 = h0p[k4];
        const float4 h1 = h1p[k4];
        const float4 h2 = h2p[k4];
        const float4 h3 = h3p[k4];
        const float4 w0 = W4lds[(k4 * 4 + 0) * 8 + cg];
        const float4 w1 = W4lds[(k4 * 4 + 1) * 8 + cg];
        const float4 w2 = W4lds[(k4 * 4 + 2) * 8 + cg];
        const float4 w3 = W4lds[(k4 * 4 + 3) * 8 + cg];

        #define FMA4(A, S, WV)                      \
            A.x = fmaf(S, WV.x, A.x);               \
            A.y = fmaf(S, WV.y, A.y);               \
            A.z = fmaf(S, WV.z, A.z);               \
            A.w = fmaf(S, WV.w, A.w);
        FMA4(acc0, h0.x, w0) FMA4(acc0, h0.y, w1) FMA4(acc0, h0.z, w2) FMA4(acc0, h0.w, w3)
        FMA4(acc1, h1.x, w0) FMA4(acc1, h1.y, w1) FMA4(acc1, h1.z, w2) FMA4(acc1, h1.w, w3)
        FMA4(acc2, h2.x, w0) FMA4(acc2, h2.y, w1) FMA4(acc2, h2.z, w2) FMA4(acc2, h2.w, w3)
        FMA4(acc3, h3.x, w0) FMA4(acc3, h3.y, w1) FMA4(acc3, h3.z, w2) FMA4(acc3, h3.w, w3)
        #undef FMA4
    }

    float4* HW4 = reinterpret_cast<float4*>(HW);
    #define STORE(I, A)                                                      \
        { const int rr = r0 + I;                                             \
          if (rr < n) HW4[(size_t)rr * (DOUT / 4) + cg] = A; }
    STORE(0, acc0) STORE(1, acc1) STORE(2, acc2) STORE(3, acc3)
    #undef STORE
}

// ---------------- Kernel 2: out = A_csr @ HW  (SpMM, float4 + deep unroll) --
__global__ __launch_bounds__(256) void spmm_kernel(
    const float* __restrict__ HWf, const int* __restrict__ rowPtr,
    const int* __restrict__ colIdx, const float* __restrict__ val,
    float* __restrict__ out, int n)
{
    const float4* HW4 = reinterpret_cast<const float4*>(HWf);
    const int gid = blockIdx.x * 256 + threadIdx.x;
    const int row = gid >> 3;
    if (row >= n) return;
    const int cg = gid & 7;

    const int start = rowPtr[row];
    const int end   = rowPtr[row + 1];
    float4 acc = {0.f, 0.f, 0.f, 0.f};

    #define GATHER_FMA(E)                                                    \
        { const int   c_ = colIdx[E];                                        \
          const float v_ = val[E];                                           \
          const float4 h_ = HW4[(size_t)c_ * (DOUT / 4) + cg];               \
          acc.x = fmaf(v_, h_.x, acc.x);                                     \
          acc.y = fmaf(v_, h_.y, acc.y);                                     \
          acc.z = fmaf(v_, h_.z, acc.z);                                     \
          acc.w = fmaf(v_, h_.w, acc.w); }

    int e = start;
    for (; e + 8 <= end; e += 8) {
        GATHER_FMA(e + 0) GATHER_FMA(e + 1) GATHER_FMA(e + 2) GATHER_FMA(e + 3)
        GATHER_FMA(e + 4) GATHER_FMA(e + 5) GATHER_FMA(e + 6) GATHER_FMA(e + 7)
    }
    for (; e + 4 <= end; e += 4) {
        GATHER_FMA(e + 0) GATHER_FMA(e + 1) GATHER_FMA(e + 2) GATHER_FMA(e + 3)
    }
    for (; e < end; ++e) { GATHER_FMA(e) }
    #undef GATHER_FMA

    reinterpret_cast<float4*>(out)[(size_t)row * (DOUT / 4) + cg] = acc;
}

// ---------------- Fallback: fused (only if ws too small) --------------------
__global__ __launch_bounds__(256) void fused_kernel(
    const float* __restrict__ H, const float* __restrict__ W,
    const int* __restrict__ rowPtr, const int* __restrict__ colIdx,
    const float* __restrict__ val, float* __restrict__ out, int n)
{
    __shared__ float Wlds[DIN * DOUT];
    for (int i = threadIdx.x; i < DIN * DOUT; i += 256) Wlds[i] = W[i];
    __syncthreads();

    const int gid = blockIdx.x * 256 + threadIdx.x;
    const int row = gid >> 5;
    if (row >= n) return;
    const int c = gid & 31;

    const int start = rowPtr[row];
    const int end   = rowPtr[row + 1];
    float acc = 0.f;
    for (int e = start; e < end; ++e) {
        const int   cidx = colIdx[e];
        const float v    = val[e];
        const float* h = H + (size_t)cidx * DIN;
        float dot = 0.f;
        #pragma unroll 8
        for (int k = 0; k < DIN; ++k)
            dot = fmaf(h[k], Wlds[k * DOUT + c], dot);
        acc = fmaf(v, dot, acc);
    }
    out[(size_t)row * DOUT + c] = acc;
}

extern "C" void kernel_launch(void* const* d_in, const int* in_sizes, int n_in,
                              void* d_out, int out_size, void* d_ws, size_t ws_size,
                              hipStream_t stream)
{
    const float* H      = (const float*)d_in[0];
    const float* W      = (const float*)d_in[1];
    const int*   rowPtr = (const int*)d_in[2];
    const int*   colIdx = (const int*)d_in[3];
    const float* val    = (const float*)d_in[4];
    float*       out    = (float*)d_out;

    const int n = in_sizes[2] - 1;           // rowPtr has N+1 entries
    const size_t hw_bytes = (size_t)n * DOUT * sizeof(float);

    if (ws_size >= hw_bytes) {
        float* HW = (float*)d_ws;
        gemm_hw_kernel<<<(n + 127) / 128, 256, 0, stream>>>(H, W, HW, n);
        const int spmm_blocks = (int)(((size_t)n * (DOUT / 4) + 255) / 256);
        spmm_kernel<<<spmm_blocks, 256, 0, stream>>>(HW, rowPtr, colIdx, val, out, n);
    } else {
        const int blocks = (int)(((size_t)n * DOUT + 255) / 256);
        fused_kernel<<<blocks, 256, 0, stream>>>(H, W, rowPtr, colIdx, val, out, n);
    }
}